// Round 2
// baseline (154.672 us; speedup 1.0000x reference)
//
#include <hip/hip_runtime.h>
#include <hip/hip_bf16.h>

// LinearStitcher, round 2: zero-LDS streaming MFMA.
// x: [16384, 4096] f32, W: [16,128,256] f32, b: [16,128] f32.
// out[:, a*128+c] = sum_k x[:, a*256+k]*W[a,c,k] + b[a,c];  out[:, 2048:] = 0.
//
// Prep kernel packs W as bf16 in the exact mfma_f32_32x32x16_bf16 B-fragment
// layout: P[a][ks(16)][n(4)][lane(64)][j(8)], so the main kernel's B loads are
// single coalesced dwordx4 per lane, L1/L2-resident (1 MB total).
// Main kernel: wave = 32 rows x 128 channels of one area; A-fragments loaded
// fp32 direct from global (lane = row lane&31, k = (lane>>5)*8+j -> 32B/lane
// contiguous, 64B/row segments), packed-converted to bf16 in register.

typedef __attribute__((ext_vector_type(8))) short bf16x8;
typedef __attribute__((ext_vector_type(16))) float f32x16;

static constexpr int NX   = 4096;
static constexpr int OW   = 4096;
static constexpr int KDIM = 256;
static constexpr int CCH  = 128;

__global__ __launch_bounds__(256)
void prep_w(const float* __restrict__ W, __hip_bfloat16* __restrict__ P) {
    const int a = blockIdx.x;          // 0..15
    const int t = threadIdx.x;
    // per area: 16 ks * 4 n * 64 lanes = 4096 slots of 8 bf16 (16B)
    for (int s = t; s < 4096; s += 256) {
        const int ks = s >> 8;
        const int n  = (s >> 6) & 3;
        const int l  = s & 63;
        const int ch = n * 32 + (l & 31);
        const int k0 = ks * 16 + (l >> 5) * 8;
        const float* src = W + ((long)a * CCH + ch) * KDIM + k0;
        const float4 w0 = *(const float4*)(src);
        const float4 w1 = *(const float4*)(src + 4);
        union { bf16x8 v; __hip_bfloat162 h[4]; } pw;
        pw.h[0] = __float22bfloat162_rn(make_float2(w0.x, w0.y));
        pw.h[1] = __float22bfloat162_rn(make_float2(w0.z, w0.w));
        pw.h[2] = __float22bfloat162_rn(make_float2(w1.x, w1.y));
        pw.h[3] = __float22bfloat162_rn(make_float2(w1.z, w1.w));
        *(bf16x8*)((char*)P + (((long)a * 4096 + s) << 4)) = pw.v;
    }
}

__global__ __launch_bounds__(256, 2)
void stitch_kernel(const float* __restrict__ x,
                   const __hip_bfloat16* __restrict__ P,
                   const float* __restrict__ bias,
                   float* __restrict__ out) {
    const int tid  = threadIdx.x;
    const int lane = tid & 63;
    const int wid  = tid >> 6;
    const int area = blockIdx.x >> 7;                    // 128 blocks per area
    const int rt   = ((blockIdx.x & 127) << 2) | wid;    // 0..511
    const int row0 = rt * 32;

    const int arow = lane & 31;   // A row within tile; also output col within n-frag
    const int khalf = lane >> 5;  // 0/1 -> k offset *8

    const float* ap = x + (long)(row0 + arow) * NX + area * KDIM + khalf * 8;
    const bf16x8* bp = (const bf16x8*)P + (long)area * 4096 + lane;

    f32x16 acc[4];
#pragma unroll
    for (int n = 0; n < 4; ++n)
#pragma unroll
        for (int r = 0; r < 16; ++r) acc[n][r] = 0.f;

    // distance-1 pipeline
    float4 a0 = *(const float4*)(ap);
    float4 a1 = *(const float4*)(ap + 4);
    bf16x8 bq0 = bp[0], bq1 = bp[64], bq2 = bp[128], bq3 = bp[192];

#pragma unroll
    for (int ks = 0; ks < 16; ++ks) {
        union { bf16x8 v; __hip_bfloat162 h[4]; } aw;
        aw.h[0] = __float22bfloat162_rn(make_float2(a0.x, a0.y));
        aw.h[1] = __float22bfloat162_rn(make_float2(a0.z, a0.w));
        aw.h[2] = __float22bfloat162_rn(make_float2(a1.x, a1.y));
        aw.h[3] = __float22bfloat162_rn(make_float2(a1.z, a1.w));
        const bf16x8 cb0 = bq0, cb1 = bq1, cb2 = bq2, cb3 = bq3;
        if (ks < 15) {
            const float* apn = ap + ((ks + 1) << 4);
            a0 = *(const float4*)(apn);
            a1 = *(const float4*)(apn + 4);
            const bf16x8* bn = bp + ((ks + 1) << 8);
            bq0 = bn[0]; bq1 = bn[64]; bq2 = bn[128]; bq3 = bn[192];
        }
        acc[0] = __builtin_amdgcn_mfma_f32_32x32x16_bf16(aw.v, cb0, acc[0], 0, 0, 0);
        acc[1] = __builtin_amdgcn_mfma_f32_32x32x16_bf16(aw.v, cb1, acc[1], 0, 0, 0);
        acc[2] = __builtin_amdgcn_mfma_f32_32x32x16_bf16(aw.v, cb2, acc[2], 0, 0, 0);
        acc[3] = __builtin_amdgcn_mfma_f32_32x32x16_bf16(aw.v, cb3, acc[3], 0, 0, 0);
    }

    // epilogue: C/D layout col = lane&31, row = (reg&3) + 8*(reg>>2) + 4*(lane>>5)
    float bv[4];
#pragma unroll
    for (int n = 0; n < 4; ++n)
        bv[n] = bias[area * CCH + n * 32 + arow];

    const long rbase = row0 + 4 * khalf;
#pragma unroll
    for (int n = 0; n < 4; ++n) {
        const int gcol = area * CCH + n * 32 + arow;
#pragma unroll
        for (int r = 0; r < 16; ++r) {
            const long grow = rbase + (r & 3) + ((r >> 2) << 3);
            out[grow * OW + gcol] = acc[n][r] + bv[n];
        }
    }

    // zero mirror half: cols 2048 + area*128 .. +128 for rows row0..row0+31
    float4* o4 = (float4*)(out + (long)row0 * OW + 2048 + area * CCH);
    const int zr = lane >> 5;       // row parity
    const int zc = lane & 31;       // 32 float4 = 128 cols
    const float4 z = {0.f, 0.f, 0.f, 0.f};
#pragma unroll
    for (int i = 0; i < 16; ++i)
        o4[(long)(2 * i + zr) * (OW / 4) + zc] = z;
}

extern "C" void kernel_launch(void* const* d_in, const int* in_sizes, int n_in,
                              void* d_out, int out_size, void* d_ws, size_t ws_size,
                              hipStream_t stream) {
    const float* x    = (const float*)d_in[0];
    const float* W    = (const float*)d_in[1];
    const float* bias = (const float*)d_in[2];
    float* out = (float*)d_out;
    __hip_bfloat16* P = (__hip_bfloat16*)d_ws;   // 1 MB packed W

    prep_w<<<16, 256, 0, stream>>>(W, P);
    stitch_kernel<<<2048, 256, 0, stream>>>(x, P, bias, out);
}

// Round 3
// 130.186 us; speedup vs baseline: 1.1881x; 1.1881x over previous
//
#include <hip/hip_runtime.h>
#include <hip/hip_bf16.h>

// LinearStitcher, round 3: LDS-staged x (double-buffered, async-split staging),
// prepacked bf16 W fragments from d_ws, 32x32x16 MFMA, one barrier per K-chunk.
// x: [16384, 4096] f32, W: [16,128,256] f32, b: [16,128] f32.
// out[:, a*128+c] = sum_k x[:, a*256+k]*W[a,c,k] + b[a,c];  out[:, 2048:] = 0.

typedef __attribute__((ext_vector_type(8))) short bf16x8;
typedef __attribute__((ext_vector_type(16))) float f32x16;

static constexpr int NX   = 4096;
static constexpr int OW   = 4096;
static constexpr int KDIM = 256;
static constexpr int CCH  = 128;

// P[a][ks(16)][n(4)][lane(64)] : bf16x8 (16B) in exact 32x32x16 B-fragment layout
__global__ __launch_bounds__(256)
void prep_w(const float* __restrict__ W, __hip_bfloat16* __restrict__ P) {
    const int a = blockIdx.x;          // 0..15
    const int t = threadIdx.x;
    for (int s = t; s < 4096; s += 256) {
        const int ks = s >> 8;
        const int n  = (s >> 6) & 3;
        const int l  = s & 63;
        const int ch = n * 32 + (l & 31);
        const int k0 = ks * 16 + (l >> 5) * 8;
        const float* src = W + ((long)a * CCH + ch) * KDIM + k0;
        const float4 w0 = *(const float4*)(src);
        const float4 w1 = *(const float4*)(src + 4);
        union { bf16x8 v; __hip_bfloat162 h[4]; } pw;
        pw.h[0] = __float22bfloat162_rn(make_float2(w0.x, w0.y));
        pw.h[1] = __float22bfloat162_rn(make_float2(w0.z, w0.w));
        pw.h[2] = __float22bfloat162_rn(make_float2(w1.x, w1.y));
        pw.h[3] = __float22bfloat162_rn(make_float2(w1.z, w1.w));
        *(bf16x8*)((char*)P + (((long)a * 4096 + s) << 4)) = pw.v;
    }
}

__global__ __launch_bounds__(256, 3)
void stitch_kernel(const float* __restrict__ x,
                   const __hip_bfloat16* __restrict__ Pw,
                   const float* __restrict__ bias,
                   float* __restrict__ out) {
    const int tid  = threadIdx.x;
    const int lane = tid & 63;
    const int wid  = tid >> 6;                 // 0..3 -> 32-row band
    const int area = blockIdx.x & 15;
    const int rt   = blockIdx.x >> 4;          // 0..127
    const int row0 = rt * 128;

    // LDS: two chunks of [128 rows][64 k] bf16 = 16KB each, XOR-swizzled rows.
    __shared__ char As[2][128 * 128];

    f32x16 acc[4];
#pragma unroll
    for (int n = 0; n < 4; ++n)
#pragma unroll
        for (int r = 0; r < 16; ++r) acc[n][r] = 0.f;

    // staging: thread covers rows sr+16i (i=0..7), 4 floats at col scf
    const int sr  = tid >> 4;                  // 0..15
    const int scf = (tid & 15) << 2;           // 0..60 (floats)
    const float* xb = x + (long)(row0 + sr) * NX + area * KDIM + scf;

    float4 sreg[8];
#pragma unroll
    for (int i = 0; i < 8; ++i)
        sreg[i] = *(const float4*)(xb + ((long)i << 4) * NX);

    // convert + write chunk 0
#pragma unroll
    for (int i = 0; i < 8; ++i) {
        const int r = sr + (i << 4);
        int off = (r << 7) + (scf << 1);
        off ^= (r & 7) << 4;
        union { unsigned long long u; __hip_bfloat162 h[2]; } pw;
        pw.h[0] = __float22bfloat162_rn(make_float2(sreg[i].x, sreg[i].y));
        pw.h[1] = __float22bfloat162_rn(make_float2(sreg[i].z, sreg[i].w));
        *(unsigned long long*)(&As[0][off]) = pw.u;
    }
    __syncthreads();

    const int arow = lane & 31;
    const int kh   = lane >> 5;
    const int wrow0 = wid << 5;
    const bf16x8* bpa = (const bf16x8*)Pw + (long)area * 4096 + lane;

#pragma unroll
    for (int c = 0; c < 4; ++c) {
        // issue next chunk's global loads early (latency hides under compute)
        if (c < 3) {
            const float* xn = xb + (c + 1) * 64;
#pragma unroll
            for (int i = 0; i < 8; ++i)
                sreg[i] = *(const float4*)(xn + ((long)i << 4) * NX);
        }
        // compute chunk c from As[c&1]
#pragma unroll
        for (int ks = 0; ks < 4; ++ks) {
            const int row = wrow0 + arow;
            int off = (row << 7) + (ks << 5) + (kh << 4);
            off ^= (row & 7) << 4;
            const bf16x8 af = *(const bf16x8*)(&As[c & 1][off]);
            const bf16x8* bn = bpa + ((long)(c * 4 + ks) << 8);
            const bf16x8 b0 = bn[0], b1 = bn[64], b2 = bn[128], b3 = bn[192];
            acc[0] = __builtin_amdgcn_mfma_f32_32x32x16_bf16(af, b0, acc[0], 0, 0, 0);
            acc[1] = __builtin_amdgcn_mfma_f32_32x32x16_bf16(af, b1, acc[1], 0, 0, 0);
            acc[2] = __builtin_amdgcn_mfma_f32_32x32x16_bf16(af, b2, acc[2], 0, 0, 0);
            acc[3] = __builtin_amdgcn_mfma_f32_32x32x16_bf16(af, b3, acc[3], 0, 0, 0);
        }
        // convert + write next chunk into the other buffer, then barrier
        if (c < 3) {
#pragma unroll
            for (int i = 0; i < 8; ++i) {
                const int r = sr + (i << 4);
                int off = (r << 7) + (scf << 1);
                off ^= (r & 7) << 4;
                union { unsigned long long u; __hip_bfloat162 h[2]; } pw;
                pw.h[0] = __float22bfloat162_rn(make_float2(sreg[i].x, sreg[i].y));
                pw.h[1] = __float22bfloat162_rn(make_float2(sreg[i].z, sreg[i].w));
                *(unsigned long long*)(&As[(c + 1) & 1][off]) = pw.u;
            }
            __syncthreads();
        }
    }

    // epilogue: C/D layout col = lane&31, row = (reg&3) + 8*(reg>>2) + 4*(lane>>5)
    float bv[4];
#pragma unroll
    for (int n = 0; n < 4; ++n)
        bv[n] = bias[area * CCH + n * 32 + arow];

    const long rbase = row0 + wrow0 + 4 * kh;
#pragma unroll
    for (int n = 0; n < 4; ++n) {
        const int gcol = area * CCH + n * 32 + arow;
#pragma unroll
        for (int r = 0; r < 16; ++r) {
            const long grow = rbase + (r & 3) + ((r >> 2) << 3);
            out[grow * OW + gcol] = acc[n][r] + bv[n];
        }
    }

    // zero mirror half: rows row0..row0+127, cols 2048+area*128..+128
    float4* o4 = (float4*)(out + (long)row0 * OW + 2048 + area * CCH);
    const int zc = tid & 31;                   // 32 float4 = 128 cols
    const int zr = tid >> 5;                   // 0..7
    const float4 z = {0.f, 0.f, 0.f, 0.f};
#pragma unroll
    for (int i = 0; i < 16; ++i)
        o4[(long)(zr + (i << 3)) * (OW / 4) + zc] = z;
}

extern "C" void kernel_launch(void* const* d_in, const int* in_sizes, int n_in,
                              void* d_out, int out_size, void* d_ws, size_t ws_size,
                              hipStream_t stream) {
    const float* x    = (const float*)d_in[0];
    const float* W    = (const float*)d_in[1];
    const float* bias = (const float*)d_in[2];
    float* out = (float*)d_out;
    __hip_bfloat16* P = (__hip_bfloat16*)d_ws;   // 1 MB packed W fragments

    prep_w<<<16, 256, 0, stream>>>(W, P);
    stitch_kernel<<<2048, 256, 0, stream>>>(x, P, bias, out);
}